// Round 12
// baseline (744.482 us; speedup 1.0000x reference)
//
#include <hip/hip_runtime.h>

typedef unsigned short u16;
typedef __attribute__((ext_vector_type(8))) short short8;
typedef __attribute__((ext_vector_type(4))) float f32x4;

#define NN 128000
#define EE 512000
#define GB 128

#define GLDS16(g, l)                                                     \
  __builtin_amdgcn_global_load_lds(                                      \
      (const __attribute__((address_space(1))) unsigned int*)(g),        \
      (__attribute__((address_space(3))) unsigned int*)(l), 16, 0, 0)

__device__ __forceinline__ float u2f(u16 u) {
  union { unsigned u32; float f; } v; v.u32 = ((unsigned)u) << 16; return v.f;
}
__device__ __forceinline__ u16 f2bf(float x) {
  union { float f; unsigned u; } v; v.f = x;
  unsigned r = v.u + 0x7FFF + ((v.u >> 16) & 1);
  return (u16)(r >> 16);
}

// ---- k_prep: deg_start (bid<500) || weight transpose (bid>=500).
// ---- Independent work merged into one launch (GNN/CNN phases don't
// ---- interact until k_z0); saves a launch gap and overlaps the
// ---- latency-bound atomics with the streaming transpose.
__global__ void k_prep(const int* ei, const int* batch, int* deg, int* start, int* hist,
                       const float* w1, const float* w2, const float* w3,
                       float* w1T, u16* w2t, u16* w3p) {
  __shared__ int lh[GB];
  int tid = threadIdx.x, bid = blockIdx.x;
  if (bid < 500) {
    int blk = bid;
    if (tid < GB) lh[tid] = 0;
    __syncthreads();
    int e0 = blk * 1024;
#pragma unroll
    for (int t = 0; t < 4; t++) {
      int e = e0 + t * 256 + tid;
      int col = ei[EE + e];
      atomicAdd(&deg[col], 1);
      atomicAdd(&lh[batch[col]], 1);
    }
    int i = blk * 256 + tid;
    int b = batch[i];
    if (i == 0) start[0] = 0;
    else if (b != batch[i - 1]) start[b] = i;
    if (i == NN - 1) start[GB] = NN;
    __syncthreads();
    if (tid < GB && lh[tid]) atomicAdd(&hist[tid * 16], lh[tid]);
    return;
  }
  int idx = (bid - 500) * 256 + tid;
  if (idx < 4992) { int o = idx & 63, ck = idx >> 6; w1T[idx] = w1[o * 78 + ck]; return; }
  idx -= 4992;
  if (idx < 49152) {
    int c = idx & 63, o = (idx >> 6) & 255, k = idx >> 14;
    w2t[idx] = f2bf(w2[o * 192 + c * 3 + k]);
    return;
  }
  idx -= 49152;
  if (idx < 1310720) {
    int stcbk = idx >> 15;           // s = (st*4+cb)*5 + k, 0..39
    int fi    = (idx >> 9) & 63;     // o fragment
    int r512  = idx & 511;
    int quad  = r512 >> 7, l16 = (r512 >> 3) & 15, i = r512 & 7;
    int stcb  = stcbk / 5, k = stcbk - stcb * 5;
    int o = fi * 16 + l16;
    int c = stcb * 32 + quad * 8 + i;   // = st*128 + cb*32 + quad*8 + i
    w3p[idx] = f2bf(w3[o * 1280 + c * 5 + k]);
  }
}

// ---- exclusive prefix over 128 bins; init padded cursors
__global__ void k_prefix(const int* hist, int* off, int* cursor) {
  __shared__ int h[GB];
  int tid = threadIdx.x;
  h[tid] = hist[tid * 16];
  __syncthreads();
  int s = 0;
  for (int j = 0; j < tid; j++) s += h[j];
  off[tid] = s;
  cursor[tid * 16] = s;
  if (tid == GB - 1) off[GB] = s + h[GB - 1];
}

// ---- k_scatter_conv1: edge bucketing (bid<500) || conv1 (bid>=500).
// ---- Independent (conv1 needs only w1T from k_prep); overlays LDS via
// ---- one smem buffer so static shared = max, not sum.
__global__ void k_scatter_conv1(const int* ei, const int* batch, const int* deg, int* cursor,
                                uint2* bucket, const float* target, const float* w1T,
                                const float* b1, u16* h1T) {
  __shared__ __align__(16) char smem[33696];
  int tid = threadIdx.x, bid = blockIdx.x;
  if (bid < 500) {
    int* lh    = (int*)smem;          // [128]
    int* lbase = (int*)smem + GB;     // [128]
    int blk = bid;
    if (tid < GB) lh[tid] = 0;
    __syncthreads();
    int e0 = blk * 1024;
    int row[4], g[4], rk[4]; float nrm[4];
#pragma unroll
    for (int t = 0; t < 4; t++) {
      int e = e0 + t * 256 + tid;
      int r = ei[e], c = ei[EE + e];
      row[t] = r;
      g[t] = batch[c];
      int dr = deg[r], dc = deg[c];
      float fr = dr > 0 ? rsqrtf((float)dr) : 0.f;
      float fc = dc > 0 ? rsqrtf((float)dc) : 0.f;
      nrm[t] = fr * fc;
      rk[t] = atomicAdd(&lh[g[t]], 1);
    }
    __syncthreads();
    if (tid < GB && lh[tid]) lbase[tid] = atomicAdd(&cursor[tid * 16], lh[tid]);
    __syncthreads();
#pragma unroll
    for (int t = 0; t < 4; t++) {
      uint2 v; v.x = (unsigned)row[t]; v.y = __float_as_uint(nrm[t]);
      bucket[lbase[g[t]] + rk[t]] = v;
    }
    return;
  }
  // ---- conv1: target[bl][26][1000] -> h1T[bl][l<998][64] bf16 (relu) ----
  float (*ts)[132] = (float(*)[132])smem;          // 26*132*4 = 13728 B
  float* wls = (float*)(smem + 13728);             // 4992*4  = 19968 B
  int id = bid - 500;
  int lt = id & 7, bl = id >> 3;
  int l0 = lt * 128;
  int q = tid >> 6, lane = tid & 63;
  for (int c = q; c < 26; c += 4)
    for (int i = lane; i < 130; i += 64)
      ts[c][i] = target[(bl * 26 + c) * 1000 + min(l0 + i, 999)];
  for (int i = tid; i < 4992; i += 256) wls[i] = w1T[i];
  __syncthreads();
  int o = tid & 63, wid = tid >> 6;
  float w[78];
#pragma unroll
  for (int i = 0; i < 78; i++) w[i] = wls[i * 64 + o];
  float bias = b1[o];
  for (int t = 0; t < 32; t++) {
    int li = wid * 32 + t;
    float acc = bias;
#pragma unroll
    for (int c = 0; c < 26; c++)
#pragma unroll
      for (int k = 0; k < 3; k++) acc += ts[c][li + k] * w[c * 3 + k];
    int lg = l0 + li;
    if (lg < 998) h1T[((size_t)bl * 1000 + lg) * 64 + o] = f2bf(fmaxf(acc, 0.f));
  }
}

// ---- k_gather_conv2: 33-dim gather (odd bids) || conv2 MFMA (even bids),
// ---- interleaved so latency-bound gather waves co-reside with MFMA waves
// ---- (m114 overlap). gather33: y[g][ch] = sum_e norm_e * x[row_e][ch]
// ---- (segment-sum commutes with x@W^T -- r11 win). conv2: 3 shifted GEMMs.
__global__ void k_gather_conv2(const uint2* bucket, const int* off, const float* x, float* y,
                               const u16* h1T, const u16* w2t, const float* b2, u16* h2T) {
  __shared__ __align__(16) char smem[33024];
  int tid = threadIdx.x, bid = blockIdx.x;
  if (bid & 1) {
    // ---- gather33, idx in 0..2047: s = idx&15, g = idx>>4 ----
    float (*red)[33] = (float(*)[33])smem;
    int idx = bid >> 1;
    int s = idx & 15, g = idx >> 4;
    int lo = off[g], hi = off[g + 1];
    int cnt = hi - lo;
    int per = (cnt + 15) >> 4;
    int b0 = lo + s * per, b1 = min(b0 + per, hi);
    int lane = tid & 63, wid = tid >> 6;
    float acc = 0.f;
    if (lane < 33) {
#pragma unroll 4
      for (int e = b0 + wid; e < b1; e += 4) {
        uint2 be = bucket[e];
        float nrm = __uint_as_float(be.y);
        acc = fmaf(nrm, x[(size_t)be.x * 33 + lane], acc);
      }
      red[wid][lane] = acc;
    }
    __syncthreads();
    if (tid < 33) {
      float v = red[0][tid] + red[1][tid] + red[2][tid] + red[3][tid];
      if (v != 0.f) atomicAdd(&y[g * 33 + tid], v);
    }
    return;
  }
  // ---- conv2, idx in 0..2047: lt = idx&7, ot = (idx>>3)&1, bl = idx>>4 ----
  u16* als = (u16*)smem;             // 132*32*2  = 8448 B
  u16* bls = (u16*)(smem + 8448);    // 3*128*32*2 = 24576 B
  int idx = bid >> 1;
  int lt = idx & 7, ot = (idx >> 3) & 1, bl = idx >> 4;
  int l0 = lt * 128, o0 = ot * 128;
  int lane = tid & 63, wid = tid >> 6;
  int wm = wid >> 1, wn = wid & 1;
  int quad = lane >> 4, l16 = lane & 15;
  const f32x4 zero = {0.f, 0.f, 0.f, 0.f};
  f32x4 acc[4][4];
#pragma unroll
  for (int i = 0; i < 4; i++)
#pragma unroll
    for (int j = 0; j < 4; j++) acc[i][j] = zero;
  for (int cb = 0; cb < 2; cb++) {
    int c0 = cb * 32;
#pragma unroll
    for (int rr = 0; rr < 2; rr++) {
      int cid = rr * 256 + wid * 64 + lane;
      int row = cid >> 2, ch = (cid & 3) ^ (row & 3);
      GLDS16(h1T + ((size_t)bl * 1000 + min(l0 + row, 997)) * 64 + c0 + ch * 8,
             als + (rr * 256 + wid * 64) * 8);
    }
    if (wid == 0 && lane < 8) {
      int cid = 512 + lane;
      int row = cid >> 2, ch = (cid & 3) ^ (row & 3);
      GLDS16(h1T + ((size_t)bl * 1000 + min(l0 + row, 997)) * 64 + c0 + ch * 8, als + 512 * 8);
    }
#pragma unroll
    for (int rr = 0; rr < 6; rr++) {
      int cid = rr * 256 + wid * 64 + lane;
      int rko = cid >> 2, k = rko >> 7, o = rko & 127;
      int ch = (cid & 3) ^ (rko & 3);
      GLDS16(w2t + ((size_t)(k * 256 + o0 + o)) * 64 + c0 + ch * 8,
             bls + (rr * 256 + wid * 64) * 8);
    }
    __syncthreads();
#pragma unroll
    for (int k = 0; k < 3; k++) {
      short8 af[4], bfr[4];
#pragma unroll
      for (int i = 0; i < 4; i++) {
        int row = k + wm * 64 + i * 16 + l16;
        af[i] = *(const short8*)(als + row * 32 + ((quad ^ (row & 3)) * 8));
      }
#pragma unroll
      for (int j = 0; j < 4; j++) {
        int rowB = wn * 64 + j * 16 + l16;
        bfr[j] = *(const short8*)(bls + (k * 128 + rowB) * 32 + ((quad ^ (rowB & 3)) * 8));
      }
#pragma unroll
      for (int i = 0; i < 4; i++)
#pragma unroll
        for (int j = 0; j < 4; j++)
          acc[i][j] = __builtin_amdgcn_mfma_f32_16x16x32_bf16(af[i], bfr[j], acc[i][j], 0, 0, 0);
    }
    __syncthreads();
  }
#pragma unroll
  for (int j = 0; j < 4; j++) {
    int col = o0 + wn * 64 + j * 16 + l16;
    float bias = b2[col];
#pragma unroll
    for (int i = 0; i < 4; i++)
#pragma unroll
      for (int r = 0; r < 4; r++) {
        int lg = l0 + wm * 64 + i * 16 + quad * 4 + r;
        if (lg < 996)
          h2T[((size_t)bl * 996 + lg) * 256 + col] = f2bf(fmaxf(acc[i][j][r] + bias, 0.f));
      }
  }
}

// ---- conv3: r6 verified version (best: 257-260 us, MfmaUtil ~62, 0
// ---- conflicts). Five structural variants all lost to this config --
// ---- 2 waves/SIMD with acc[8][4] is the local optimum. Async LDS
// ---- double-buffer at constant 35 KB footprint.
__global__ void __launch_bounds__(256, 2)
k_conv3(const u16* h2T, const u16* w3p, const float* b3, float* pooledT) {
  __shared__ __align__(16) u16 als[2][1088 * 8];   // 2 x 17408 B
  __shared__ float mbuf[256];
  int bid = blockIdx.x;
  int xc = bid & 7, rr0 = bid >> 3;            // 64 blocks per XCD: 16 bl x 4 ot
  int ot = rr0 & 3, bl = xc * 16 + (rr0 >> 2);
  int o0 = ot * 256;
  int tid = threadIdx.x;
  int lane = tid & 63, wn = tid >> 6;
  int quad = lane >> 4, l16 = lane & 15;
  float omax[4];
#pragma unroll
  for (int j = 0; j < 4; j++) omax[j] = -3.0e38f;
  const f32x4 zero = {0.f, 0.f, 0.f, 0.f};
  // per-wave B base: fi = ot*16 + wn*4 (+j via +1024B offsets)
  const u16* wb = w3p + (size_t)(ot * 16 + wn * 4) * 512 + lane * 8;
  const size_t rowbase = (size_t)bl * 996;

  // ---- prologue: stage quarter (lt=0,qc=0) into als[0] ----
  {
    u16* dst = als[0];
#pragma unroll
    for (int c = 0; c < 4; c++) {
      int cid = c * 256 + tid;
      int row = cid >> 3, pp = cid & 7;
      int cc = (pp - row) & 7;                 // swizzle pp=(cc+row)&7
      GLDS16(h2T + (rowbase + min(row, 995)) * 256 + cc * 8, dst + cid * 8);
    }
    if (tid < 64) {
      int cid = 1024 + tid;
      int row = cid >> 3, pp = cid & 7;
      int cc = (pp - row) & 7;
      GLDS16(h2T + (rowbase + min(row, 995)) * 256 + cc * 8, dst + cid * 8);
    }
  }
  asm volatile("s_waitcnt vmcnt(0)" ::: "memory");
  __builtin_amdgcn_s_barrier();

  for (int lt = 0; lt < 8; lt++) {
    f32x4 acc[8][4];
#pragma unroll
    for (int i = 0; i < 8; i++)
#pragma unroll
      for (int j = 0; j < 4; j++) acc[i][j] = zero;
#pragma unroll 1
    for (int qc = 0; qc < 4; qc++) {
      const u16* a = als[qc & 1];
      // ---- peeled step (cbq=0, k=0) ----
      {
        const u16* p_ = wb + (size_t)(qc * 2) * 5 * 32768;
        short8 breg[4];
        breg[0] = *(const short8*)(p_);
        breg[1] = *(const short8*)(p_ + 512);
        breg[2] = *(const short8*)(p_ + 1024);
        breg[3] = *(const short8*)(p_ + 1536);
#pragma unroll
        for (int i = 0; i < 8; i++) {
          int row = i * 16 + l16;
          int pp = (quad + row) & 7;
          short8 af = *(const short8*)(a + row * 64 + pp * 8);
          acc[i][0] = __builtin_amdgcn_mfma_f32_16x16x32_bf16(af, breg[0], acc[i][0], 0, 0, 0);
          acc[i][1] = __builtin_amdgcn_mfma_f32_16x16x32_bf16(af, breg[1], acc[i][1], 0, 0, 0);
          acc[i][2] = __builtin_amdgcn_mfma_f32_16x16x32_bf16(af, breg[2], acc[i][2], 0, 0, 0);
          acc[i][3] = __builtin_amdgcn_mfma_f32_16x16x32_bf16(af, breg[3], acc[i][3], 0, 0, 0);
        }
      }
      // ---- stage next quarter into the other buffer ----
      if (lt * 4 + qc < 31) {
        int nqc = (qc + 1) & 3;
        int nlt = lt + (qc == 3 ? 1 : 0);
        int l0n = nlt * 128;
        u16* dst = als[(qc + 1) & 1];
#pragma unroll
        for (int c = 0; c < 4; c++) {
          int cid = c * 256 + tid;
          int row = cid >> 3, pp = cid & 7;
          int cc = (pp - row) & 7;
          GLDS16(h2T + (rowbase + min(l0n + row, 995)) * 256 + nqc * 64 + cc * 8,
                 dst + cid * 8);
        }
        if (tid < 64) {
          int cid = 1024 + tid;
          int row = cid >> 3, pp = cid & 7;
          int cc = (pp - row) & 7;
          GLDS16(h2T + (rowbase + min(l0n + row, 995)) * 256 + nqc * 64 + cc * 8,
                 dst + cid * 8);
        }
      }
      // ---- remaining 9 steps of this phase ----
#pragma unroll 1
      for (int cbq = 0; cbq < 2; cbq++) {
        int stcb = qc * 2 + cbq;
        int k0 = (cbq == 0) ? 1 : 0;
#pragma unroll
        for (int k = k0; k < 5; k++) {
          const u16* p_ = wb + (size_t)(stcb * 5 + k) * 32768;
          short8 breg[4];
          breg[0] = *(const short8*)(p_);
          breg[1] = *(const short8*)(p_ + 512);
          breg[2] = *(const short8*)(p_ + 1024);
          breg[3] = *(const short8*)(p_ + 1536);
#pragma unroll
          for (int i = 0; i < 8; i++) {
            int row = k + i * 16 + l16;
            int pp = (cbq * 4 + quad + row) & 7;
            short8 af = *(const short8*)(a + row * 64 + pp * 8);
            acc[i][0] = __builtin_amdgcn_mfma_f32_16x16x32_bf16(af, breg[0], acc[i][0], 0, 0, 0);
            acc[i][1] = __builtin_amdgcn_mfma_f32_16x16x32_bf16(af, breg[1], acc[i][1], 0, 0, 0);
            acc[i][2] = __builtin_amdgcn_mfma_f32_16x16x32_bf16(af, breg[2], acc[i][2], 0, 0, 0);
            acc[i][3] = __builtin_amdgcn_mfma_f32_16x16x32_bf16(af, breg[3], acc[i][3], 0, 0, 0);
          }
        }
      }
      // staging retired long ago (in-order vmcnt; 9 steps of B waits since) ->
      // this drain is free; barrier publishes buf[(qc+1)&1] and releases buf[qc&1]
      asm volatile("s_waitcnt vmcnt(0)" ::: "memory");
      __builtin_amdgcn_s_barrier();
    }
    // fold l-tile into running per-o max (mask rows >= 992)
    int l0 = lt * 128;
#pragma unroll
    for (int i = 0; i < 8; i++) {
#pragma unroll
      for (int r = 0; r < 4; r++) {
        int lg = l0 + i * 16 + quad * 4 + r;
        if (lg < 992) {
#pragma unroll
          for (int j = 0; j < 4; j++) omax[j] = fmaxf(omax[j], acc[i][j][r]);
        }
      }
    }
  }
#pragma unroll
  for (int j = 0; j < 4; j++) {
    omax[j] = fmaxf(omax[j], __shfl_xor(omax[j], 16, 64));
    omax[j] = fmaxf(omax[j], __shfl_xor(omax[j], 32, 64));
  }
  if (quad == 0) {
#pragma unroll
    for (int j = 0; j < 4; j++) mbuf[wn * 64 + j * 16 + l16] = omax[j];
  }
  __syncthreads();
  {
    float v = mbuf[tid] + b3[o0 + tid];
    pooledT[(size_t)(o0 + tid) * 128 + bl] = fmaxf(v, 0.f);
  }
}

// ---- z0T[r][b]: drug rows fuse the tiny y[128][33] @ lin_w[256][33]^T
// ---- matvec (the deferred linear map) with /cnt + lin_b
__global__ void k_z0(const float* y, const int* start, const float* lin_w, const float* lin_b,
                     const float* tgtT, float* z0T) {
  int idx = blockIdx.x * 256 + threadIdx.x;
  int r = idx >> 7, bb = idx & 127;
  float v;
  if (r < 256) {
    float cnt = (float)(start[bb + 1] - start[bb]);
    const float* yr = y + bb * 33;
    const float* wr = lin_w + r * 33;
    float acc = 0.f;
#pragma unroll
    for (int i = 0; i < 33; i++) acc = fmaf(yr[i], wr[i], acc);
    v = acc / cnt + lin_b[r];
  } else {
    v = tgtT[(r - 256) * 128 + bb];
  }
  z0T[idx] = v;
}

// ---- big fc layers (relu): 512 threads, 4 output rows per block
__global__ void k_fc4(const float* zT, const float* W, const float* bias, float* outT,
                      int K, int O) {
  __shared__ float wls[4 * 1024];
  int tid = threadIdx.x;
  int o0 = blockIdx.x * 4;
  for (int idx = tid; idx < 4 * K; idx += 512) {
    int oo = idx / K, i = idx - oo * K;
    wls[oo * K + i] = W[(size_t)(o0 + oo) * K + i];
  }
  __syncthreads();
  int osub = tid >> 7, bb = tid & 127;
  int o = o0 + osub;
  float acc = 0.f;
  const float* wp = &wls[osub * K];
#pragma unroll 8
  for (int i = 0; i < K; i++) acc = fmaf(wp[i], zT[i * 128 + bb], acc);
  acc += bias[o];
  outT[(size_t)o * 128 + bb] = fmaxf(acc, 0.f);
}

// ---- final fc layer (O=1, no relu) -> d_out
__global__ void k_fc_final(const float* zT, const float* W, const float* bias, float* final_out,
                           int K) {
  __shared__ float wls[512];
  int tid = threadIdx.x;
  for (int i = tid; i < K; i += 256) wls[i] = W[i];
  __syncthreads();
  if (tid >= 128) return;
  int bb = tid;
  float acc = 0.f;
#pragma unroll 8
  for (int i = 0; i < K; i++) acc = fmaf(wls[i], zT[i * 128 + bb], acc);
  final_out[bb] = acc + bias[0];
}

extern "C" void kernel_launch(void* const* d_in, const int* in_sizes, int n_in,
                              void* d_out, int out_size, void* d_ws, size_t ws_size,
                              hipStream_t stream) {
  const float* x      = (const float*)d_in[0];
  const int*   ei     = (const int*)d_in[1];
  const int*   batch  = (const int*)d_in[2];
  const float* target = (const float*)d_in[3];
  const float* lin_w  = (const float*)d_in[4];
  const float* lin_b  = (const float*)d_in[5];
  const float* w1     = (const float*)d_in[6];
  const float* b1     = (const float*)d_in[7];
  const float* w2     = (const float*)d_in[8];
  const float* b2     = (const float*)d_in[9];
  const float* w3     = (const float*)d_in[10];
  const float* b3     = (const float*)d_in[11];
  const float* fcw    = (const float*)d_in[12];
  const float* fcb    = (const float*)d_in[13];
  const float* m1w = (const float*)d_in[14]; const float* m1b = (const float*)d_in[15];
  const float* m2w = (const float*)d_in[16]; const float* m2b = (const float*)d_in[17];
  const float* m3w = (const float*)d_in[18]; const float* m3b = (const float*)d_in[19];
  const float* m4w = (const float*)d_in[20]; const float* m4b = (const float*)d_in[21];

  char* ws = (char*)d_ws;
  size_t ofs = 0;
  auto alloc = [&](size_t bytes) -> void* {
    void* p = ws + ofs;
    ofs = (ofs + bytes + 255) & ~(size_t)255;
    return p;
  };
  // ---- persistent region ----
  int*   deg    = (int*)alloc((size_t)NN * 4);
  int*   start  = (int*)alloc((size_t)(GB + 1) * 4);
  int*   hist   = (int*)alloc((size_t)GB * 16 * 4);
  int*   off    = (int*)alloc((size_t)(GB + 1) * 4);
  int*   cursor = (int*)alloc((size_t)GB * 16 * 4);
  uint2* bucket = (uint2*)alloc((size_t)EE * 8);
  float* y      = (float*)alloc((size_t)GB * 33 * 4);
  float* w1T    = (float*)alloc((size_t)78 * 64 * 4);
  u16*   w2t    = (u16*)alloc((size_t)3 * 256 * 64 * 2);
  u16*   w3p    = (u16*)alloc((size_t)5 * 1024 * 256 * 2);
  float* pooledT= (float*)alloc((size_t)1024 * 128 * 4);
  float* tgtT   = (float*)alloc((size_t)768 * 128 * 4);
  float* z0T    = (float*)alloc((size_t)1024 * 128 * 4);
  float* z1T    = (float*)alloc((size_t)1024 * 128 * 4);
  float* z2T    = (float*)alloc((size_t)1024 * 128 * 4);
  float* z3T    = (float*)alloc((size_t)512 * 128 * 4);
  size_t F_end = ofs;

  // ---- dynamic region: h1T+h2T (CNN) ----
  u16* h1T = (u16*)(ws + F_end);
  u16* h2T = (u16*)(ws + F_end + (size_t)128 * 1000 * 64 * 2);

  hipMemsetAsync(deg, 0, (size_t)NN * 4, stream);
  hipMemsetAsync(hist, 0, (size_t)GB * 16 * 4, stream);
  hipMemsetAsync(y, 0, (size_t)GB * 33 * 4, stream);

  // ---- fused GNN + CNN front-end ----
  k_prep<<<5832, 256, 0, stream>>>(ei, batch, deg, start, hist, w1, w2, w3, w1T, w2t, w3p);
  k_prefix<<<1, 128, 0, stream>>>(hist, off, cursor);
  k_scatter_conv1<<<1524, 256, 0, stream>>>(ei, batch, deg, cursor, bucket,
                                            target, w1T, b1, h1T);
  k_gather_conv2<<<4096, 256, 0, stream>>>(bucket, off, x, y, h1T, w2t, b2, h2T);
  k_conv3<<<512, 256, 0, stream>>>(h2T, w3p, b3, pooledT);

  // ---- head ----
  k_fc4<<<192, 512, 0, stream>>>(pooledT, fcw, fcb, tgtT, 1024, 768);
  k_z0<<<512, 256, 0, stream>>>(y, start, lin_w, lin_b, tgtT, z0T);
  k_fc4<<<256, 512, 0, stream>>>(z0T, m1w, m1b, z1T, 1024, 1024);
  k_fc4<<<256, 512, 0, stream>>>(z1T, m2w, m2b, z2T, 1024, 1024);
  k_fc4<<<128, 512, 0, stream>>>(z2T, m3w, m3b, z3T, 1024, 512);
  k_fc_final<<<1, 256, 0, stream>>>(z3T, m4w, m4b, (float*)d_out, 512);
}

// Round 13
// 736.528 us; speedup vs baseline: 1.0108x; 1.0108x over previous
//
#include <hip/hip_runtime.h>

typedef unsigned short u16;
typedef __attribute__((ext_vector_type(8))) short short8;
typedef __attribute__((ext_vector_type(4))) float f32x4;

#define NN 128000
#define EE 512000
#define GB 128

#define GLDS16(g, l)                                                     \
  __builtin_amdgcn_global_load_lds(                                      \
      (const __attribute__((address_space(1))) unsigned int*)(g),        \
      (__attribute__((address_space(3))) unsigned int*)(l), 16, 0, 0)

__device__ __forceinline__ float u2f(u16 u) {
  union { unsigned u32; float f; } v; v.u32 = ((unsigned)u) << 16; return v.f;
}
__device__ __forceinline__ u16 f2bf(float x) {
  union { float f; unsigned u; } v; v.f = x;
  unsigned r = v.u + 0x7FFF + ((v.u >> 16) & 1);
  return (u16)(r >> 16);
}

// ---- weight prep: w1T[78][64] f32,
// ---- w2p: conv3-style B fragments for conv2 [s=h*3+tap][fi=o>>4][quad|l16|i8]
// ----      (s stride 8192 u16 = 16 KB, fi stride 512 u16 = 1 KB); ch = h*32+quad*8+i.
// ---- w3p: step-major B fragments [s=stcb*5+k][fi=o>>4][quad4][l16_16][i8] bf16
// ----      (step stride 32768 u16 = 64 KB, fi stride 512 u16 = 1 KB).
__global__ void k_transpose(const float* w1, const float* w2, const float* w3,
                            float* w1T, u16* w2p, u16* w3p) {
  int idx = blockIdx.x * 256 + threadIdx.x;
  if (idx < 4992) { int o = idx & 63, ck = idx >> 6; w1T[idx] = w1[o * 78 + ck]; return; }
  idx -= 4992;
  if (idx < 49152) {
    int s    = idx >> 13;            // 0..5
    int r    = idx & 8191;
    int fi   = r >> 9;               // 0..15
    int r512 = r & 511;
    int quad = r512 >> 7, l16 = (r512 >> 3) & 15, i = r512 & 7;
    int h = s / 3, tap = s - h * 3;
    int o = fi * 16 + l16;
    int c = h * 32 + quad * 8 + i;
    w2p[idx] = f2bf(w2[o * 192 + c * 3 + tap]);
    return;
  }
  idx -= 49152;
  if (idx < 1310720) {
    int stcbk = idx >> 15;           // s = (st*4+cb)*5 + k, 0..39
    int fi    = (idx >> 9) & 63;     // o fragment
    int r512  = idx & 511;
    int quad  = r512 >> 7, l16 = (r512 >> 3) & 15, i = r512 & 7;
    int stcb  = stcbk / 5, k = stcbk - stcb * 5;
    int o = fi * 16 + l16;
    int c = stcb * 32 + quad * 8 + i;   // = st*128 + cb*32 + quad*8 + i
    w3p[idx] = f2bf(w3[o * 1280 + c * 5 + k]);
  }
}

// ---- in-degree over col; per-graph edge histogram; graph boundaries
__global__ void k_deg_start(const int* ei, const int* batch, int* deg, int* start, int* hist) {
  __shared__ int lh[GB];
  int tid = threadIdx.x, blk = blockIdx.x;
  if (tid < GB) lh[tid] = 0;
  __syncthreads();
  int e0 = blk * 1024;
#pragma unroll
  for (int t = 0; t < 4; t++) {
    int e = e0 + t * 256 + tid;
    int col = ei[EE + e];
    atomicAdd(&deg[col], 1);
    atomicAdd(&lh[batch[col]], 1);
  }
  int i = blk * 256 + tid;
  int b = batch[i];
  if (i == 0) start[0] = 0;
  else if (b != batch[i - 1]) start[b] = i;
  if (i == NN - 1) start[GB] = NN;
  __syncthreads();
  if (tid < GB && lh[tid]) atomicAdd(&hist[tid * 16], lh[tid]);
}

// ---- exclusive prefix over 128 bins; init padded cursors
__global__ void k_prefix(const int* hist, int* off, int* cursor) {
  __shared__ int h[GB];
  int tid = threadIdx.x;
  h[tid] = hist[tid * 16];
  __syncthreads();
  int s = 0;
  for (int j = 0; j < tid; j++) s += h[j];
  off[tid] = s;
  cursor[tid * 16] = s;
  if (tid == GB - 1) off[GB] = s + h[GB - 1];
}

// ---- bucket edges by graph of col; norm computed inline from deg
__global__ void k_scatter(const int* ei, const int* batch, const int* deg,
                          int* cursor, uint2* bucket) {
  __shared__ int lh[GB];
  __shared__ int lbase[GB];
  int tid = threadIdx.x, blk = blockIdx.x;
  if (tid < GB) lh[tid] = 0;
  __syncthreads();
  int e0 = blk * 1024;
  int row[4], g[4], rk[4]; float nrm[4];
#pragma unroll
  for (int t = 0; t < 4; t++) {
    int e = e0 + t * 256 + tid;
    int r = ei[e], c = ei[EE + e];
    row[t] = r;
    g[t] = batch[c];
    int dr = deg[r], dc = deg[c];
    float fr = dr > 0 ? rsqrtf((float)dr) : 0.f;
    float fc = dc > 0 ? rsqrtf((float)dc) : 0.f;
    nrm[t] = fr * fc;
    rk[t] = atomicAdd(&lh[g[t]], 1);
  }
  __syncthreads();
  if (tid < GB && lh[tid]) lbase[tid] = atomicAdd(&cursor[tid * 16], lh[tid]);
  __syncthreads();
#pragma unroll
  for (int t = 0; t < 4; t++) {
    uint2 v; v.x = (unsigned)row[t]; v.y = __float_as_uint(nrm[t]);
    bucket[lbase[g[t]] + rk[t]] = v;
  }
}

// ---- 33-dim per-graph gather: y[g][ch] = sum_e norm_e * x[row_e][ch]
// ---- (segment-sum commutes with x@W^T -- r11 win). 16 splits/graph.
__global__ void k_gather33(const uint2* bucket, const int* off, const float* x, float* y) {
  __shared__ float red[4][33];
  int tid = threadIdx.x;
  int s = blockIdx.x, g = blockIdx.y;
  int lo = off[g], hi = off[g + 1];
  int cnt = hi - lo;
  int per = (cnt + 15) >> 4;
  int b0 = lo + s * per, b1 = min(b0 + per, hi);
  int lane = tid & 63, wid = tid >> 6;
  float acc = 0.f;
  if (lane < 33) {
#pragma unroll 4
    for (int e = b0 + wid; e < b1; e += 4) {
      uint2 be = bucket[e];
      float nrm = __uint_as_float(be.y);
      acc = fmaf(nrm, x[(size_t)be.x * 33 + lane], acc);
    }
    red[wid][lane] = acc;
  }
  __syncthreads();
  if (tid < 33) {
    float v = red[0][tid] + red[1][tid] + red[2][tid] + red[3][tid];
    if (v != 0.f) atomicAdd(&y[g * 33 + tid], v);
  }
}

// ---- conv1: target[bl][26][1000] -> h1T[bl][l<998][64] bf16 channel-last (relu)
__global__ void k_conv1(const float* target, const float* w1T, const float* b1, u16* h1T) {
  __shared__ float ts[26][132];
  __shared__ float wls[78 * 64];
  int tid = threadIdx.x, lt = blockIdx.x, bl = blockIdx.y;
  int l0 = lt * 128;
  int q = tid >> 6, lane = tid & 63;
  for (int c = q; c < 26; c += 4)
    for (int i = lane; i < 130; i += 64)
      ts[c][i] = target[(bl * 26 + c) * 1000 + min(l0 + i, 999)];
  for (int i = tid; i < 4992; i += 256) wls[i] = w1T[i];
  __syncthreads();
  int o = tid & 63, wid = tid >> 6;
  float w[78];
#pragma unroll
  for (int i = 0; i < 78; i++) w[i] = wls[i * 64 + o];
  float bias = b1[o];
  for (int t = 0; t < 32; t++) {
    int li = wid * 32 + t;
    float acc = bias;
#pragma unroll
    for (int c = 0; c < 26; c++)
#pragma unroll
      for (int k = 0; k < 3; k++) acc += ts[c][li + k] * w[c * 3 + k];
    int lg = l0 + li;
    if (lg < 998) h1T[((size_t)bl * 1000 + lg) * 64 + o] = f2bf(fmaxf(acc, 0.f));
  }
}

// ---- conv2p: conv3-chassis port. One block = full 128 l x 256 o tile, K=192.
// ---- A-window 132x64 ch (16.9 KB) staged ONCE with conv3's verified swizzle;
// ---- ONE barrier (vs old 4); B = conv3-style register fragments from
// ---- L2-resident w2p (h plays cbq's role, tap plays k's). acc[8][4],
// ---- unroll-1 h loop (anti-spill, r8 lesson). Grid 1024 = 8 XCD x 16 bl x 8 lt.
__global__ void __launch_bounds__(256, 2)
k_conv2p(const u16* h1T, const u16* w2p, const float* b2, u16* h2T) {
  __shared__ __align__(16) u16 als[1056 * 8];   // 132 rows x 64 ch = 16896 B
  int bid = blockIdx.x;
  int xc = bid & 7, rr0 = bid >> 3;            // 128 per XCD: 16 bl x 8 lt
  int lt = rr0 & 7, bl = xc * 16 + (rr0 >> 3);
  int l0 = lt * 128;
  int tid = threadIdx.x;
  int lane = tid & 63, wn = tid >> 6;
  int quad = lane >> 4, l16 = lane & 15;
  const f32x4 zero = {0.f, 0.f, 0.f, 0.f};
  f32x4 acc[8][4];
#pragma unroll
  for (int i = 0; i < 8; i++)
#pragma unroll
    for (int j = 0; j < 4; j++) acc[i][j] = zero;
  // per-wave B base: fi = wn*4 (+j via +1024B offsets)
  const u16* wb = w2p + (size_t)(wn * 4) * 512 + lane * 8;
  const size_t rowbase = (size_t)bl * 1000;
  // ---- stage A window: 1056 chunks, swizzle pp=(cc+row)&7 ----
#pragma unroll
  for (int c = 0; c < 4; c++) {
    int cid = c * 256 + tid;
    int row = cid >> 3, pp = cid & 7;
    int cc = (pp - row) & 7;
    GLDS16(h1T + (rowbase + min(l0 + row, 997)) * 64 + cc * 8, als + cid * 8);
  }
  if (tid < 32) {
    int cid = 1024 + tid;
    int row = cid >> 3, pp = cid & 7;
    int cc = (pp - row) & 7;
    GLDS16(h1T + (rowbase + min(l0 + row, 997)) * 64 + cc * 8, als + cid * 8);
  }
  asm volatile("s_waitcnt vmcnt(0)" ::: "memory");
  __syncthreads();
  // ---- 6 K-steps (h 2 x tap 3), 32 MFMA each ----
#pragma unroll 1
  for (int h = 0; h < 2; h++) {
#pragma unroll
    for (int tap = 0; tap < 3; tap++) {
      const u16* p_ = wb + (size_t)(h * 3 + tap) * 8192;
      short8 breg[4];
      breg[0] = *(const short8*)(p_);
      breg[1] = *(const short8*)(p_ + 512);
      breg[2] = *(const short8*)(p_ + 1024);
      breg[3] = *(const short8*)(p_ + 1536);
#pragma unroll
      for (int i = 0; i < 8; i++) {
        int row = tap + i * 16 + l16;
        int pp = (h * 4 + quad + row) & 7;
        short8 af = *(const short8*)(als + row * 64 + pp * 8);
        acc[i][0] = __builtin_amdgcn_mfma_f32_16x16x32_bf16(af, breg[0], acc[i][0], 0, 0, 0);
        acc[i][1] = __builtin_amdgcn_mfma_f32_16x16x32_bf16(af, breg[1], acc[i][1], 0, 0, 0);
        acc[i][2] = __builtin_amdgcn_mfma_f32_16x16x32_bf16(af, breg[2], acc[i][2], 0, 0, 0);
        acc[i][3] = __builtin_amdgcn_mfma_f32_16x16x32_bf16(af, breg[3], acc[i][3], 0, 0, 0);
      }
    }
  }
  // ---- epilogue: bias + relu + store (mask lg >= 996) ----
#pragma unroll
  for (int j = 0; j < 4; j++) {
    int col = wn * 64 + j * 16 + l16;
    float bias = b2[col];
#pragma unroll
    for (int i = 0; i < 8; i++)
#pragma unroll
      for (int r = 0; r < 4; r++) {
        int lg = l0 + i * 16 + quad * 4 + r;
        if (lg < 996)
          h2T[((size_t)bl * 996 + lg) * 256 + col] = f2bf(fmaxf(acc[i][j][r] + bias, 0.f));
      }
  }
}

// ---- conv3: r6 verified version (best: 257-260 us, MfmaUtil ~62, 0
// ---- conflicts). Five structural variants all lost to this config --
// ---- 2 waves/SIMD with acc[8][4] is the local optimum. Async LDS
// ---- double-buffer at constant 35 KB footprint.
__global__ void __launch_bounds__(256, 2)
k_conv3(const u16* h2T, const u16* w3p, const float* b3, float* pooledT) {
  __shared__ __align__(16) u16 als[2][1088 * 8];   // 2 x 17408 B
  __shared__ float mbuf[256];
  int bid = blockIdx.x;
  int xc = bid & 7, rr0 = bid >> 3;            // 64 blocks per XCD: 16 bl x 4 ot
  int ot = rr0 & 3, bl = xc * 16 + (rr0 >> 2);
  int o0 = ot * 256;
  int tid = threadIdx.x;
  int lane = tid & 63, wn = tid >> 6;
  int quad = lane >> 4, l16 = lane & 15;
  float omax[4];
#pragma unroll
  for (int j = 0; j < 4; j++) omax[j] = -3.0e38f;
  const f32x4 zero = {0.f, 0.f, 0.f, 0.f};
  // per-wave B base: fi = ot*16 + wn*4 (+j via +1024B offsets)
  const u16* wb = w3p + (size_t)(ot * 16 + wn * 4) * 512 + lane * 8;
  const size_t rowbase = (size_t)bl * 996;

  // ---- prologue: stage quarter (lt=0,qc=0) into als[0] ----
  {
    u16* dst = als[0];
#pragma unroll
    for (int c = 0; c < 4; c++) {
      int cid = c * 256 + tid;
      int row = cid >> 3, pp = cid & 7;
      int cc = (pp - row) & 7;                 // swizzle pp=(cc+row)&7
      GLDS16(h2T + (rowbase + min(row, 995)) * 256 + cc * 8, dst + cid * 8);
    }
    if (tid < 64) {
      int cid = 1024 + tid;
      int row = cid >> 3, pp = cid & 7;
      int cc = (pp - row) & 7;
      GLDS16(h2T + (rowbase + min(row, 995)) * 256 + cc * 8, dst + cid * 8);
    }
  }
  asm volatile("s_waitcnt vmcnt(0)" ::: "memory");
  __builtin_amdgcn_s_barrier();

  for (int lt = 0; lt < 8; lt++) {
    f32x4 acc[8][4];
#pragma unroll
    for (int i = 0; i < 8; i++)
#pragma unroll
      for (int j = 0; j < 4; j++) acc[i][j] = zero;
#pragma unroll 1
    for (int qc = 0; qc < 4; qc++) {
      const u16* a = als[qc & 1];
      // ---- peeled step (cbq=0, k=0) ----
      {
        const u16* p_ = wb + (size_t)(qc * 2) * 5 * 32768;
        short8 breg[4];
        breg[0] = *(const short8*)(p_);
        breg[1] = *(const short8*)(p_ + 512);
        breg[2] = *(const short8*)(p_ + 1024);
        breg[3] = *(const short8*)(p_ + 1536);
#pragma unroll
        for (int i = 0; i < 8; i++) {
          int row = i * 16 + l16;
          int pp = (quad + row) & 7;
          short8 af = *(const short8*)(a + row * 64 + pp * 8);
          acc[i][0] = __builtin_amdgcn_mfma_f32_16x16x32_bf16(af, breg[0], acc[i][0], 0, 0, 0);
          acc[i][1] = __builtin_amdgcn_mfma_f32_16x16x32_bf16(af, breg[1], acc[i][1], 0, 0, 0);
          acc[i][2] = __builtin_amdgcn_mfma_f32_16x16x32_bf16(af, breg[2], acc[i][2], 0, 0, 0);
          acc[i][3] = __builtin_amdgcn_mfma_f32_16x16x32_bf16(af, breg[3], acc[i][3], 0, 0, 0);
        }
      }
      // ---- stage next quarter into the other buffer ----
      if (lt * 4 + qc < 31) {
        int nqc = (qc + 1) & 3;
        int nlt = lt + (qc == 3 ? 1 : 0);
        int l0n = nlt * 128;
        u16* dst = als[(qc + 1) & 1];
#pragma unroll
        for (int c = 0; c < 4; c++) {
          int cid = c * 256 + tid;
          int row = cid >> 3, pp = cid & 7;
          int cc = (pp - row) & 7;
          GLDS16(h2T + (rowbase + min(l0n + row, 995)) * 256 + nqc * 64 + cc * 8,
                 dst + cid * 8);
        }
        if (tid < 64) {
          int cid = 1024 + tid;
          int row = cid >> 3, pp = cid & 7;
          int cc = (pp - row) & 7;
          GLDS16(h2T + (rowbase + min(l0n + row, 995)) * 256 + nqc * 64 + cc * 8,
                 dst + cid * 8);
        }
      }
      // ---- remaining 9 steps of this phase ----
#pragma unroll 1
      for (int cbq = 0; cbq < 2; cbq++) {
        int stcb = qc * 2 + cbq;
        int k0 = (cbq == 0) ? 1 : 0;
#pragma unroll
        for (int k = k0; k < 5; k++) {
          const u16* p_ = wb + (size_t)(stcb * 5 + k) * 32768;
          short8 breg[4];
          breg[0] = *(const short8*)(p_);
          breg[1] = *(const short8*)(p_ + 512);
          breg[2] = *(const short8*)(p_ + 1024);
          breg[3] = *(const short8*)(p_ + 1536);
#pragma unroll
          for (int i = 0; i < 8; i++) {
            int row = k + i * 16 + l16;
            int pp = (cbq * 4 + quad + row) & 7;
            short8 af = *(const short8*)(a + row * 64 + pp * 8);
            acc[i][0] = __builtin_amdgcn_mfma_f32_16x16x32_bf16(af, breg[0], acc[i][0], 0, 0, 0);
            acc[i][1] = __builtin_amdgcn_mfma_f32_16x16x32_bf16(af, breg[1], acc[i][1], 0, 0, 0);
            acc[i][2] = __builtin_amdgcn_mfma_f32_16x16x32_bf16(af, breg[2], acc[i][2], 0, 0, 0);
            acc[i][3] = __builtin_amdgcn_mfma_f32_16x16x32_bf16(af, breg[3], acc[i][3], 0, 0, 0);
          }
        }
      }
      // staging retired long ago (in-order vmcnt; 9 steps of B waits since) ->
      // this drain is free; barrier publishes buf[(qc+1)&1] and releases buf[qc&1]
      asm volatile("s_waitcnt vmcnt(0)" ::: "memory");
      __builtin_amdgcn_s_barrier();
    }
    // fold l-tile into running per-o max (mask rows >= 992)
    int l0 = lt * 128;
#pragma unroll
    for (int i = 0; i < 8; i++) {
#pragma unroll
      for (int r = 0; r < 4; r++) {
        int lg = l0 + i * 16 + quad * 4 + r;
        if (lg < 992) {
#pragma unroll
          for (int j = 0; j < 4; j++) omax[j] = fmaxf(omax[j], acc[i][j][r]);
        }
      }
    }
  }
#pragma unroll
  for (int j = 0; j < 4; j++) {
    omax[j] = fmaxf(omax[j], __shfl_xor(omax[j], 16, 64));
    omax[j] = fmaxf(omax[j], __shfl_xor(omax[j], 32, 64));
  }
  if (quad == 0) {
#pragma unroll
    for (int j = 0; j < 4; j++) mbuf[wn * 64 + j * 16 + l16] = omax[j];
  }
  __syncthreads();
  {
    float v = mbuf[tid] + b3[o0 + tid];
    pooledT[(size_t)(o0 + tid) * 128 + bl] = fmaxf(v, 0.f);
  }
}

// ---- z0T[r][b]: drug rows fuse the tiny y[128][33] @ lin_w[256][33]^T
// ---- matvec (the deferred linear map) with /cnt + lin_b
__global__ void k_z0(const float* y, const int* start, const float* lin_w, const float* lin_b,
                     const float* tgtT, float* z0T) {
  int idx = blockIdx.x * 256 + threadIdx.x;
  int r = idx >> 7, bb = idx & 127;
  float v;
  if (r < 256) {
    float cnt = (float)(start[bb + 1] - start[bb]);
    const float* yr = y + bb * 33;
    const float* wr = lin_w + r * 33;
    float acc = 0.f;
#pragma unroll
    for (int i = 0; i < 33; i++) acc = fmaf(yr[i], wr[i], acc);
    v = acc / cnt + lin_b[r];
  } else {
    v = tgtT[(r - 256) * 128 + bb];
  }
  z0T[idx] = v;
}

// ---- big fc layers (relu): 512 threads, 4 output rows per block
__global__ void k_fc4(const float* zT, const float* W, const float* bias, float* outT,
                      int K, int O) {
  __shared__ float wls[4 * 1024];
  int tid = threadIdx.x;
  int o0 = blockIdx.x * 4;
  for (int idx = tid; idx < 4 * K; idx += 512) {
    int oo = idx / K, i = idx - oo * K;
    wls[oo * K + i] = W[(size_t)(o0 + oo) * K + i];
  }
  __syncthreads();
  int osub = tid >> 7, bb = tid & 127;
  int o = o0 + osub;
  float acc = 0.f;
  const float* wp = &wls[osub * K];
#pragma unroll 8
  for (int i = 0; i < K; i++) acc = fmaf(wp[i], zT[i * 128 + bb], acc);
  acc += bias[o];
  outT[(size_t)o * 128 + bb] = fmaxf(acc, 0.f);
}

// ---- final fc layer (O=1, no relu) -> d_out
__global__ void k_fc_final(const float* zT, const float* W, const float* bias, float* final_out,
                           int K) {
  __shared__ float wls[512];
  int tid = threadIdx.x;
  for (int i = tid; i < K; i += 256) wls[i] = W[i];
  __syncthreads();
  if (tid >= 128) return;
  int bb = tid;
  float acc = 0.f;
#pragma unroll 8
  for (int i = 0; i < K; i++) acc = fmaf(wls[i], zT[i * 128 + bb], acc);
  final_out[bb] = acc + bias[0];
}

extern "C" void kernel_launch(void* const* d_in, const int* in_sizes, int n_in,
                              void* d_out, int out_size, void* d_ws, size_t ws_size,
                              hipStream_t stream) {
  const float* x      = (const float*)d_in[0];
  const int*   ei     = (const int*)d_in[1];
  const int*   batch  = (const int*)d_in[2];
  const float* target = (const float*)d_in[3];
  const float* lin_w  = (const float*)d_in[4];
  const float* lin_b  = (const float*)d_in[5];
  const float* w1     = (const float*)d_in[6];
  const float* b1     = (const float*)d_in[7];
  const float* w2     = (const float*)d_in[8];
  const float* b2     = (const float*)d_in[9];
  const float* w3     = (const float*)d_in[10];
  const float* b3     = (const float*)d_in[11];
  const float* fcw    = (const float*)d_in[12];
  const float* fcb    = (const float*)d_in[13];
  const float* m1w = (const float*)d_in[14]; const float* m1b = (const float*)d_in[15];
  const float* m2w = (const float*)d_in[16]; const float* m2b = (const float*)d_in[17];
  const float* m3w = (const float*)d_in[18]; const float* m3b = (const float*)d_in[19];
  const float* m4w = (const float*)d_in[20]; const float* m4b = (const float*)d_in[21];

  char* ws = (char*)d_ws;
  size_t ofs = 0;
  auto alloc = [&](size_t bytes) -> void* {
    void* p = ws + ofs;
    ofs = (ofs + bytes + 255) & ~(size_t)255;
    return p;
  };
  // ---- persistent region ----
  int*   deg    = (int*)alloc((size_t)NN * 4);
  int*   start  = (int*)alloc((size_t)(GB + 1) * 4);
  int*   hist   = (int*)alloc((size_t)GB * 16 * 4);
  int*   off    = (int*)alloc((size_t)(GB + 1) * 4);
  int*   cursor = (int*)alloc((size_t)GB * 16 * 4);
  uint2* bucket = (uint2*)alloc((size_t)EE * 8);
  float* y      = (float*)alloc((size_t)GB * 33 * 4);
  float* w1T    = (float*)alloc((size_t)78 * 64 * 4);
  u16*   w2p    = (u16*)alloc((size_t)6 * 16 * 512 * 2);
  u16*   w3p    = (u16*)alloc((size_t)5 * 1024 * 256 * 2);
  float* pooledT= (float*)alloc((size_t)1024 * 128 * 4);
  float* tgtT   = (float*)alloc((size_t)768 * 128 * 4);
  float* z0T    = (float*)alloc((size_t)1024 * 128 * 4);
  float* z1T    = (float*)alloc((size_t)1024 * 128 * 4);
  float* z2T    = (float*)alloc((size_t)1024 * 128 * 4);
  float* z3T    = (float*)alloc((size_t)512 * 128 * 4);
  size_t F_end = ofs;

  // ---- dynamic region: h1T+h2T (CNN) ----
  u16* h1T = (u16*)(ws + F_end);
  u16* h2T = (u16*)(ws + F_end + (size_t)128 * 1000 * 64 * 2);

  hipMemsetAsync(deg, 0, (size_t)NN * 4, stream);
  hipMemsetAsync(hist, 0, (size_t)GB * 16 * 4, stream);
  hipMemsetAsync(y, 0, (size_t)GB * 33 * 4, stream);

  // ---- GNN phase (33-dim gather) ----
  k_transpose<<<5332, 256, 0, stream>>>(w1, w2, w3, w1T, w2p, w3p);
  k_deg_start<<<500, 256, 0, stream>>>(ei, batch, deg, start, hist);
  k_prefix<<<1, 128, 0, stream>>>(hist, off, cursor);
  k_scatter<<<500, 256, 0, stream>>>(ei, batch, deg, cursor, bucket);
  k_gather33<<<dim3(16, GB), 256, 0, stream>>>(bucket, off, x, y);

  // ---- CNN phase ----
  k_conv1<<<dim3(8, 128), 256, 0, stream>>>(target, w1T, b1, h1T);
  k_conv2p<<<1024, 256, 0, stream>>>(h1T, w2p, b2, h2T);
  k_conv3<<<512, 256, 0, stream>>>(h2T, w3p, b3, pooledT);

  // ---- head ----
  k_fc4<<<192, 512, 0, stream>>>(pooledT, fcw, fcb, tgtT, 1024, 768);
  k_z0<<<512, 256, 0, stream>>>(y, start, lin_w, lin_b, tgtT, z0T);
  k_fc4<<<256, 512, 0, stream>>>(z0T, m1w, m1b, z1T, 1024, 1024);
  k_fc4<<<256, 512, 0, stream>>>(z1T, m2w, m2b, z2T, 1024, 1024);
  k_fc4<<<128, 512, 0, stream>>>(z2T, m3w, m3b, z3T, 1024, 512);
  k_fc_final<<<1, 256, 0, stream>>>(z3T, m4w, m4b, (float*)d_out, 512);
}